// Round 3
// baseline (361.932 us; speedup 1.0000x reference)
//
#include <hip/hip_runtime.h>

#define SEQ 4096
#define DM 1024
#define DS 64
#define KS 64

#define TCH 64            // channels per block
#define TT  64            // t outputs per block
#define R   8             // outputs per thread

// ---------------------------------------------------------------------------
// async global->LDS helper (16B per lane; LDS dest = wave-uniform base + lane*16)
// ---------------------------------------------------------------------------
typedef const __attribute__((address_space(1))) void* gas_ptr;
typedef __attribute__((address_space(3))) void* las_ptr;
__device__ __forceinline__ void async_cp16(const void* g, void* s) {
    __builtin_amdgcn_global_load_lds((gas_ptr)g, (las_ptr)s, 16, 0, 0);
}

// ---------------------------------------------------------------------------
// Kernel 1: csum[d] = sum_m C[m, d]
// ---------------------------------------------------------------------------
__global__ void csum_kernel(const float* __restrict__ C, float* __restrict__ csum) {
    int d    = threadIdx.x & 63;
    int mloc = threadIdx.x >> 6;
    int m0   = blockIdx.x * 64;
    float s = 0.f;
#pragma unroll
    for (int j = 0; j < 16; ++j)
        s += C[(m0 + j * 4 + mloc) * DS + d];
    __shared__ float red[4][64];
    red[mloc][d] = s;
    __syncthreads();
    if (threadIdx.x < 64) {
        float t = red[0][d] + red[1][d] + red[2][d] + red[3][d];
        atomicAdd(&csum[d], t);
    }
}

// ---------------------------------------------------------------------------
// Kernel 2: Ktl[l*DM + k] = sum_d csum[d] * exp(A[d]*dt[k]*l) * B[d, k]
// ---------------------------------------------------------------------------
__global__ void taps_kernel(const float* __restrict__ A, const float* __restrict__ B,
                            const float* __restrict__ log_dt,
                            const float* __restrict__ csum, float* __restrict__ Ktl) {
    int g = blockIdx.x * blockDim.x + threadIdx.x;
    int k = g & (DM - 1);
    int l = g >> 10;
    float dt = __expf(log_dt[k]);
    float fl = (float)l;
    float acc = 0.f;
#pragma unroll 8
    for (int d = 0; d < DS; ++d)
        acc += csum[d] * __expf(A[d] * dt * fl) * B[d * DM + k];
    Ktl[g] = acc;
}

// ---------------------------------------------------------------------------
// Main conv. Taps in LDS (16 KB, staged once, ONE barrier); u read directly
// from global into a circular 16-slot register window. Per thread: channel
// pair c2, outputs o0..o0+7. Slide load for row o0+22-l issued at iter l,
// first used 9-16 iters (~300-500 VALU cycles) later -> L1/L2 latency hidden.
// Per-block u working set = 32 KB (L1-sized), 8x reuse across t-groups.
// y[b,t,k] = D[k]*u[b,t,k] + sum_l Kt[l,k]*u[b,t+31-l,k]
// ---------------------------------------------------------------------------
template<bool GUARD>
__device__ __forceinline__ void conv_compute(
    const float* __restrict__ up,          // &u[b][o0][k0 + 2*c2]
    const float* __restrict__ smem_t,
    int c2, int o0, float2 D2, float2* acc)
{
    const float2* tp = (const float2*)smem_t;   // [l][32]

    // window w[m&15] holds u row o0 + m - 32; init m = 55..70 (rows o0+23..o0+38)
    float2 w[16];
#pragma unroll
    for (int m = 55; m <= 70; ++m) {
        int a = m - 32;
        float2 v = make_float2(0.f, 0.f);
        if (!GUARD || ((unsigned)(o0 + a) < SEQ))
            v = *(const float2*)(up + (ptrdiff_t)a * DM);
        w[m & 15] = v;
    }

#pragma unroll
    for (int l = 0; l < 64; ++l) {
        float2 t2 = tp[l * 32 + c2];
#pragma unroll
        for (int r = 0; r < R; ++r) {
            float2 uv = w[(r + 63 - l) & 15];
            acc[r].x = fmaf(t2.x, uv.x, acc[r].x);
            acc[r].y = fmaf(t2.y, uv.y, acc[r].y);
        }
        if (l == 31) {   // window slots m = r+32 hold u[o0+r]: fold in D*u
#pragma unroll
            for (int r = 0; r < R; ++r) {
                float2 uv = w[(r + 32) & 15];
                acc[r].x = fmaf(D2.x, uv.x, acc[r].x);
                acc[r].y = fmaf(D2.y, uv.y, acc[r].y);
            }
        }
        if (l <= 54) {   // slide: row o0+22-l, first used at iter l+9
            int a = 22 - l;
            float2 v = make_float2(0.f, 0.f);
            if (!GUARD || ((unsigned)(o0 + a) < SEQ))
                v = *(const float2*)(up + (ptrdiff_t)a * DM);
            w[(54 - l) & 15] = v;
        }
    }
}

__global__ __launch_bounds__(256, 4)
void conv_kernel(const float* __restrict__ u, const float* __restrict__ Ktl,
                 const float* __restrict__ D, float* __restrict__ y) {
    __shared__ __align__(16) float smem_t[KS * TCH];    // 16 KB, row stride 256B

    int k0 = blockIdx.x * TCH;
    int t0 = blockIdx.y * TT;
    int b  = blockIdx.z;

    int lane = threadIdx.x & 63;
    int wv   = threadIdx.x >> 6;

    // ---- stage taps: 16 KB = 4 iters x 4KB ----
#pragma unroll
    for (int j = 0; j < 4; ++j) {
        int fb = j * 4096 + wv * 1024;          // wave-uniform byte offset
        int f  = fb + lane * 16;
        int l  = f >> 8;
        int c  = (f & 255) >> 2;
        async_cp16(Ktl + l * DM + k0 + c, (char*)smem_t + fb);
    }
    __syncthreads();   // drains vmcnt -> taps visible; the ONLY barrier

    int c2 = threadIdx.x & 31;          // channel-pair lane
    int tg = threadIdx.x >> 5;          // t-group 0..7
    int o0 = t0 + tg * R;

    const float* up = u + ((size_t)b * SEQ + o0) * DM + k0 + 2 * c2;
    float2 D2 = *(const float2*)(D + k0 + 2 * c2);

    float2 acc[R];
#pragma unroll
    for (int r = 0; r < R; ++r) acc[r] = make_float2(0.f, 0.f);

    bool interior = (blockIdx.y > 0) && (blockIdx.y + 1 < SEQ / TT);
    if (interior)
        conv_compute<false>(up, smem_t, c2, o0, D2, acc);
    else
        conv_compute<true>(up, smem_t, c2, o0, D2, acc);

    float2* yp = (float2*)y + ((size_t)b * SEQ + o0) * (DM / 2) + (k0 >> 1) + c2;
#pragma unroll
    for (int r = 0; r < R; ++r)
        yp[(size_t)r * (DM / 2)] = acc[r];
}

// ---------------------------------------------------------------------------
extern "C" void kernel_launch(void* const* d_in, const int* in_sizes, int n_in,
                              void* d_out, int out_size, void* d_ws, size_t ws_size,
                              hipStream_t stream) {
    const float* u      = (const float*)d_in[0];
    const float* A      = (const float*)d_in[1];
    const float* Bp     = (const float*)d_in[2];
    const float* Cp     = (const float*)d_in[3];
    const float* Dp     = (const float*)d_in[4];
    const float* log_dt = (const float*)d_in[5];
    float* y = (float*)d_out;

    float* csum = (float*)d_ws;            // 64 floats
    float* Ktl  = csum + 64;               // 65536 floats, [l][k]

    hipMemsetAsync(csum, 0, DS * sizeof(float), stream);
    csum_kernel<<<16, 256, 0, stream>>>(Cp, csum);
    taps_kernel<<<(DM * KS) / 256, 256, 0, stream>>>(A, Bp, log_dt, csum, Ktl);

    dim3 grid(DM / TCH, SEQ / TT, 8);
    conv_kernel<<<grid, 256, 0, stream>>>(u, Ktl, Dp, y);
}

// Round 5
// 307.990 us; speedup vs baseline: 1.1751x; 1.1751x over previous
//
#include <hip/hip_runtime.h>

#define SEQ 4096
#define DM 1024
#define DS 64
#define KS 64

#define TCH 64             // channels per block
#define STEP 64            // outputs per step
#define NSTEP 8            // steps per block
#define OUTB (STEP*NSTEP)  // 512 outputs per block
#define R 8                // outputs per thread per step
#define NROW 128           // rows per tile: [t-32, t+95]

// ---------------------------------------------------------------------------
// async global->LDS helper (16B per lane; LDS dest = wave-uniform base + lane*16)
// ---------------------------------------------------------------------------
typedef const __attribute__((address_space(1))) void* gas_ptr;
typedef __attribute__((address_space(3))) void* las_ptr;
__device__ __forceinline__ void async_cp16(const void* g, void* s) {
    __builtin_amdgcn_global_load_lds((gas_ptr)g, (las_ptr)s, 16, 0, 0);
}

// ---------------------------------------------------------------------------
// Kernel 1: csum[d] = sum_m C[m, d]
// ---------------------------------------------------------------------------
__global__ void csum_kernel(const float* __restrict__ C, float* __restrict__ csum) {
    int d    = threadIdx.x & 63;
    int mloc = threadIdx.x >> 6;
    int m0   = blockIdx.x * 64;
    float s = 0.f;
#pragma unroll
    for (int j = 0; j < 16; ++j)
        s += C[(m0 + j * 4 + mloc) * DS + d];
    __shared__ float red[4][64];
    red[mloc][d] = s;
    __syncthreads();
    if (threadIdx.x < 64) {
        float t = red[0][d] + red[1][d] + red[2][d] + red[3][d];
        atomicAdd(&csum[d], t);
    }
}

// ---------------------------------------------------------------------------
// Kernel 2: Ktl[l*DM + k] = sum_d csum[d] * exp(A[d]*dt[k]*l) * B[d, k]
// ---------------------------------------------------------------------------
__global__ void taps_kernel(const float* __restrict__ A, const float* __restrict__ B,
                            const float* __restrict__ log_dt,
                            const float* __restrict__ csum, float* __restrict__ Ktl) {
    int g = blockIdx.x * blockDim.x + threadIdx.x;
    int k = g & (DM - 1);
    int l = g >> 10;
    float dt = __expf(log_dt[k]);
    float fl = (float)l;
    float acc = 0.f;
#pragma unroll 8
    for (int d = 0; d < DS; ++d)
        acc += csum[d] * __expf(A[d] * dt * fl) * B[d * DM + k];
    Ktl[g] = acc;
}

// ---------------------------------------------------------------------------
// Main conv. Persistent block: 8 steps x 64 outputs; taps staged once; two
// full 128-row tiles ping-pong so the stage of tile s+1 (issued BEFORE the
// compute of tile s) hides under ~4000 cycles of FMA. One barrier per step.
// Compute is R1's circular register window: all LDS reads are one runtime
// base + compile-time immediate offsets (no modular slot math -> no VGPR
// bloat, no scratch).
// y[b,t,k] = D[k]*u[b,t,k] + sum_l Kt[l,k]*u[b,t+31-l,k]
// ---------------------------------------------------------------------------
__device__ __forceinline__ void stage_tile(const float* __restrict__ ub, int a0,
                                           char* dst, int lane, int wv, int tix,
                                           bool guard) {
    if (!guard) {   // 32 KB = 8 iters x 4KB, async direct-to-LDS
#pragma unroll
        for (int j = 0; j < 8; ++j) {
            int fb = j * 4096 + wv * 1024;      // wave-uniform byte offset
            int f  = fb + lane * 16;
            int r  = f >> 8;
            int c  = (f & 255) >> 2;
            async_cp16(ub + (size_t)(a0 + r) * DM + c, dst + fb);
        }
    } else {        // guarded VGPR path, zero-fill OOB rows
#pragma unroll
        for (int j = 0; j < 8; ++j) {
            int f = j * 4096 + tix * 16;
            int r = f >> 8;
            int c = (f & 255) >> 2;
            int a = a0 + r;
            float4 v = make_float4(0.f, 0.f, 0.f, 0.f);
            if ((unsigned)a < SEQ)
                v = *(const float4*)(ub + (size_t)a * DM + c);
            *(float4*)(dst + f) = v;
        }
    }
}

__global__ __launch_bounds__(256, 2)
void conv_kernel(const float* __restrict__ u, const float* __restrict__ Ktl,
                 const float* __restrict__ D, float* __restrict__ y) {
    __shared__ __align__(16) float smem_u[2 * NROW * TCH];   // 2 x 32 KB ping-pong
    __shared__ __align__(16) float smem_t[KS * TCH];         // 16 KB taps

    int k0 = blockIdx.x * TCH;
    int ts = blockIdx.y * OUTB;
    int b  = blockIdx.z;

    int tix  = threadIdx.x;
    int lane = tix & 63;
    int wv   = tix >> 6;

    const float* ub = u + (size_t)b * SEQ * DM + k0;

    // ---- stage taps once: 16 KB = 4 iters x 4KB ----
#pragma unroll
    for (int j = 0; j < 4; ++j) {
        int fb = j * 4096 + wv * 1024;
        int f  = fb + lane * 16;
        int l  = f >> 8;
        int c  = (f & 255) >> 2;
        async_cp16(Ktl + l * DM + k0 + c, (char*)smem_t + fb);
    }

    // ---- prologue: tile 0 = rows [ts-32, ts+95] ----
    stage_tile(ub, ts - 32, (char*)smem_u, lane, wv, tix, blockIdx.y == 0);
    __syncthreads();    // drains vmcnt: taps + tile0 visible

    int c2 = tix & 31;          // channel-pair lane
    int tg = tix >> 5;          // t-group 0..7
    int rb = tg * R;

    const float2* tp = (const float2*)smem_t;   // [l][32]
    float2 D2 = *(const float2*)(D + k0 + 2 * c2);
    float2* yb = (float2*)y + (size_t)b * SEQ * (DM / 2) + (k0 >> 1) + c2;

    int cur = 0;
#pragma unroll 1
    for (int s = 0; s < NSTEP; ++s) {
        int t = ts + s * STEP;

        // ---- issue stage of tile s+1 = rows [t+32, t+159] (hidden under FMA) ----
        if (s < NSTEP - 1) {
            int a0n = t + 32;
            stage_tile(ub, a0n, (char*)(smem_u + (cur ^ 1) * (NROW * TCH)),
                       lane, wv, tix, a0n + NROW > SEQ);
        }

        // ---- compute outputs [t, t+64) from buf[cur] ----
        const float2* usb = (const float2*)(smem_u + cur * (NROW * TCH)); // [row][32]
        int o0 = t + tg * R;

        float2 acc[R];
#pragma unroll
        for (int r = 0; r < R; ++r) acc[r] = make_float2(0.f, 0.f);

        // window w[m&15] holds tile row rb+m = u row o0 + m - 32; init m = 55..70
        float2 w[16];
#pragma unroll
        for (int m = 55; m <= 70; ++m)
            w[m & 15] = usb[(rb + m) * 32 + c2];

#pragma unroll
        for (int l = 0; l < 64; ++l) {
            float2 t2 = tp[l * 32 + c2];
#pragma unroll
            for (int r = 0; r < R; ++r) {
                float2 uv = w[(r + 63 - l) & 15];
                acc[r].x = fmaf(t2.x, uv.x, acc[r].x);
                acc[r].y = fmaf(t2.y, uv.y, acc[r].y);
            }
            if (l == 31) {   // window slots m = r+32 hold u[o0+r]: fold in D*u
#pragma unroll
                for (int r = 0; r < R; ++r) {
                    float2 uv = w[(r + 32) & 15];
                    acc[r].x = fmaf(D2.x, uv.x, acc[r].x);
                    acc[r].y = fmaf(D2.y, uv.y, acc[r].y);
                }
            }
            if (l <= 54) {   // slide: row o0+22-l, first used at iter l+9
                w[(54 - l) & 15] = usb[(rb + 54 - l) * 32 + c2];
            }
        }

        float2* yp = yb + (size_t)o0 * (DM / 2);
#pragma unroll
        for (int r = 0; r < R; ++r)
            yp[(size_t)r * (DM / 2)] = acc[r];

        __syncthreads();   // tile s+1 loads drained; buf[cur] now dead
        cur ^= 1;
    }
}

// ---------------------------------------------------------------------------
extern "C" void kernel_launch(void* const* d_in, const int* in_sizes, int n_in,
                              void* d_out, int out_size, void* d_ws, size_t ws_size,
                              hipStream_t stream) {
    const float* u      = (const float*)d_in[0];
    const float* A      = (const float*)d_in[1];
    const float* Bp     = (const float*)d_in[2];
    const float* Cp     = (const float*)d_in[3];
    const float* Dp     = (const float*)d_in[4];
    const float* log_dt = (const float*)d_in[5];
    float* y = (float*)d_out;

    float* csum = (float*)d_ws;            // 64 floats
    float* Ktl  = csum + 64;               // 65536 floats, [l][k]

    hipMemsetAsync(csum, 0, DS * sizeof(float), stream);
    csum_kernel<<<16, 256, 0, stream>>>(Cp, csum);
    taps_kernel<<<(DM * KS) / 256, 256, 0, stream>>>(A, Bp, log_dt, csum, Ktl);

    dim3 grid(DM / TCH, SEQ / OUTB, 8);
    conv_kernel<<<grid, 256, 0, stream>>>(u, Ktl, Dp, y);
}

// Round 6
// 296.378 us; speedup vs baseline: 1.2212x; 1.0392x over previous
//
#include <hip/hip_runtime.h>

#define SEQ 4096
#define DM 1024
#define DS 64
#define KS 64

#define TCH 64            // channels per block
#define TT  64            // t outputs per block
#define R   8             // outputs per thread
#define NROW (TT + 64)    // 128 staged rows: t in [t0-32, t0+95]

// ---------------------------------------------------------------------------
// async global->LDS helper (16B per lane; LDS dest = wave-uniform base + lane*16)
// ---------------------------------------------------------------------------
typedef const __attribute__((address_space(1))) void* gas_ptr;
typedef __attribute__((address_space(3))) void* las_ptr;
__device__ __forceinline__ void async_cp16(const void* g, void* s) {
    __builtin_amdgcn_global_load_lds((gas_ptr)g, (las_ptr)s, 16, 0, 0);
}

// ---------------------------------------------------------------------------
// Kernel 1: csum[d] = sum_m C[m, d]
// ---------------------------------------------------------------------------
__global__ void csum_kernel(const float* __restrict__ C, float* __restrict__ csum) {
    int d    = threadIdx.x & 63;
    int mloc = threadIdx.x >> 6;
    int m0   = blockIdx.x * 64;
    float s = 0.f;
#pragma unroll
    for (int j = 0; j < 16; ++j)
        s += C[(m0 + j * 4 + mloc) * DS + d];
    __shared__ float red[4][64];
    red[mloc][d] = s;
    __syncthreads();
    if (threadIdx.x < 64) {
        float t = red[0][d] + red[1][d] + red[2][d] + red[3][d];
        atomicAdd(&csum[d], t);
    }
}

// ---------------------------------------------------------------------------
// Kernel 2: Ktl[l*DM + k] = sum_d csum[d] * exp(A[d]*dt[k]*l) * B[d, k]
// ---------------------------------------------------------------------------
__global__ void taps_kernel(const float* __restrict__ A, const float* __restrict__ B,
                            const float* __restrict__ log_dt,
                            const float* __restrict__ csum, float* __restrict__ Ktl) {
    int g = blockIdx.x * blockDim.x + threadIdx.x;
    int k = g & (DM - 1);
    int l = g >> 10;
    float dt = __expf(log_dt[k]);
    float fl = (float)l;
    float acc = 0.f;
#pragma unroll 8
    for (int d = 0; d < DS; ++d)
        acc += csum[d] * __expf(A[d] * dt * fl) * B[d * DM + k];
    Ktl[g] = acc;
}

// ---------------------------------------------------------------------------
// Main conv. u tile in LDS (32 KB only -> 5 blocks/CU); taps read DIRECTLY
// from global: full Ktl is 256 KB = permanently L2/L3-resident, each l-row
// is one coalesced 256B line shared by all 8 waves, and the fully-unrolled
// l-loop lets the compiler hoist tap loads many iterations ahead.
// Single-shot block (stage -> one barrier -> compute) keeps VGPR ~84-100:
// the persistent variants (R2/R5) both bloated to 128 + scratch spill.
// y[b,t,k] = D[k]*u[b,t,k] + sum_l Kt[l,k]*u[b,t+31-l,k]
// ---------------------------------------------------------------------------
__global__ __launch_bounds__(256, 2)
void conv_kernel(const float* __restrict__ u, const float* __restrict__ Ktl,
                 const float* __restrict__ D, float* __restrict__ y) {
    __shared__ __align__(16) float smem_u[NROW * TCH];   // 32 KB, row stride 256B

    int k0 = blockIdx.x * TCH;
    int t0 = blockIdx.y * TT;
    int b  = blockIdx.z;

    int lane = threadIdx.x & 63;
    int wv   = threadIdx.x >> 6;

    const float* gt = u + (size_t)b * SEQ * DM + (size_t)(t0 - 32) * DM + k0; // tile origin (row 0 = t0-32)

    bool interior = (blockIdx.y > 0) && (blockIdx.y + 1 < SEQ / TT);

    // ---- stage u tile: 32 KB = 8 iters x 4KB ----
    if (interior) {
#pragma unroll
        for (int j = 0; j < 8; ++j) {
            int fb = j * 4096 + wv * 1024;      // wave-uniform byte offset
            int f  = fb + lane * 16;
            int r  = f >> 8;
            int c  = (f & 255) >> 2;
            async_cp16(gt + (size_t)r * DM + c, (char*)smem_u + fb);
        }
    } else {
        // guarded VGPR path, zero-fill OOB rows
#pragma unroll
        for (int j = 0; j < 8; ++j) {
            int f = j * 4096 + threadIdx.x * 16;
            int r = f >> 8;
            int c = (f & 255) >> 2;
            int t = t0 - 32 + r;
            float4 v = make_float4(0.f, 0.f, 0.f, 0.f);
            if (t >= 0 && t < SEQ)
                v = *(const float4*)(gt + (size_t)r * DM + c);
            *(float4*)((char*)smem_u + f) = v;
        }
    }
    __syncthreads();   // the ONLY barrier

    // ---- compute: circular 16-slot window over tile rows ----
    int c2 = threadIdx.x & 31;          // channel-pair lane
    int tg = threadIdx.x >> 5;          // t-group 0..7
    int ts = t0 + tg * R;
    int rb = tg * R;                    // row(ts + r + 31 - l) = rb + r + 63 - l

    const float2* us = (const float2*)smem_u;           // [row][32]
    const float2* tK = (const float2*)(Ktl + k0);       // [l][DM/2], global (L2)

    float2 acc[R];
#pragma unroll
    for (int r = 0; r < R; ++r) acc[r] = make_float2(0.f, 0.f);

    float2 D2 = *(const float2*)(D + k0 + 2 * c2);

    // init window: rows m = 55..70 (m relative to rb); slot = m & 15
    float2 w[16];
#pragma unroll
    for (int m = 55; m <= 70; ++m)
        w[m & 15] = us[(rb + m) * 32 + c2];

#pragma unroll
    for (int l = 0; l < 64; ++l) {
        float2 t2 = tK[(size_t)l * (DM / 2) + c2];
#pragma unroll
        for (int r = 0; r < R; ++r) {
            float2 uv = w[(r + 63 - l) & 15];
            acc[r].x = fmaf(t2.x, uv.x, acc[r].x);
            acc[r].y = fmaf(t2.y, uv.y, acc[r].y);
        }
        if (l == 31) {   // window slots m = r+32 hold u[ts+r]: fold in D*u
#pragma unroll
            for (int r = 0; r < R; ++r) {
                float2 uv = w[(r + 32) & 15];
                acc[r].x = fmaf(D2.x, uv.x, acc[r].x);
                acc[r].y = fmaf(D2.y, uv.y, acc[r].y);
            }
        }
        if (l <= 54) {   // prefetch row m = 54-l (first used at iter l+16)
            int m = 54 - l;
            w[m & 15] = us[(rb + m) * 32 + c2];
        }
    }

    float2* yp2 = (float2*)y + (size_t)b * SEQ * (DM / 2) + (size_t)ts * (DM / 2) + (k0 >> 1) + c2;
#pragma unroll
    for (int r = 0; r < R; ++r)
        yp2[(size_t)r * (DM / 2)] = acc[r];
}

// ---------------------------------------------------------------------------
extern "C" void kernel_launch(void* const* d_in, const int* in_sizes, int n_in,
                              void* d_out, int out_size, void* d_ws, size_t ws_size,
                              hipStream_t stream) {
    const float* u      = (const float*)d_in[0];
    const float* A      = (const float*)d_in[1];
    const float* Bp     = (const float*)d_in[2];
    const float* Cp     = (const float*)d_in[3];
    const float* Dp     = (const float*)d_in[4];
    const float* log_dt = (const float*)d_in[5];
    float* y = (float*)d_out;

    float* csum = (float*)d_ws;            // 64 floats
    float* Ktl  = csum + 64;               // 65536 floats, [l][k]

    hipMemsetAsync(csum, 0, DS * sizeof(float), stream);
    csum_kernel<<<16, 256, 0, stream>>>(Cp, csum);
    taps_kernel<<<(DM * KS) / 256, 256, 0, stream>>>(A, Bp, log_dt, csum, Ktl);

    dim3 grid(DM / TCH, SEQ / TT, 8);
    conv_kernel<<<grid, 256, 0, stream>>>(u, Ktl, Dp, y);
}